// Round 1
// 2511.842 us; speedup vs baseline: 1.8126x; 1.8126x over previous
//
#include <hip/hip_runtime.h>
#include <hip/hip_bf16.h>

typedef short short8 __attribute__((ext_vector_type(8)));
typedef _Float16 half8 __attribute__((ext_vector_type(8)));
typedef float f32x4 __attribute__((ext_vector_type(4)));
typedef unsigned int uint;
typedef unsigned short ushort;
typedef unsigned long long u64;

static constexpr int T_SEQ = 256;
static constexpr int NB    = 64;
static constexpr int HDIM  = 512;
static constexpr int KIN   = 1024;
static constexpr int NSLOT_ALL = 8192;  // max #runs (len>=1) over 64x256 grid
static constexpr int NSLOT2    = 5504;  // max #runs with len>=2 (<= 64*ceil(257/3)=5440)

#define MFMA_BF16 __builtin_amdgcn_mfma_f32_16x16x32_bf16
#define MFMA_F16  __builtin_amdgcn_mfma_f32_16x16x32_f16

__device__ __forceinline__ float sigf(float x) { return 1.0f / (1.0f + __expf(-x)); }
__device__ __forceinline__ float tanh_fast(float x) {
  x = fminf(fmaxf(x, -15.0f), 15.0f);
  float e = __expf(2.0f * x);
  return (e - 1.0f) / (e + 1.0f);
}
__device__ __forceinline__ ushort f2bfu(float v) {
  __hip_bfloat16 b = __float2bfloat16(v);
  ushort u; __builtin_memcpy(&u, &b, 2); return u;
}
__device__ __forceinline__ float bfu2f(ushort u) {
  __hip_bfloat16 b; __builtin_memcpy(&b, &u, 2); return __bfloat162float(b);
}
__device__ __forceinline__ ushort f2h16u(float v) {
  _Float16 h = (_Float16)v;
  ushort u; __builtin_memcpy(&u, &h, 2); return u;
}

// ---- fp32 -> fp16 (ushort bits) -------------------------------------------
__global__ void conv_f16_kernel(const float* __restrict__ src,
                                ushort* __restrict__ dst, int n) {
  int i = blockIdx.x * blockDim.x + threadIdx.x;
  if (i < n) dst[i] = f2h16u(src[i]);
}

// ---- fp32 -> bf16 hi + lo split (for W_hh 3-term path) --------------------
__global__ void split_kernel(const float* __restrict__ src,
                             __hip_bfloat16* __restrict__ hi,
                             __hip_bfloat16* __restrict__ lo, int n) {
  int i = blockIdx.x * blockDim.x + threadIdx.x;
  if (i < n) {
    float v = src[i];
    __hip_bfloat16 h = __float2bfloat16(v);
    hi[i] = h;
    lo[i] = __float2bfloat16(v - __bfloat162float(h));
  }
}

// ---- mask segmentation + counting-sort by length (desc) --------------------
// A zero mask resets (h,c) to 0, so the recurrence factorizes into
// independent runs of consecutive mask=1 positions. Sort runs by length
// descending so the active set at depth k is the dense prefix [0, nk[k]).
// slotPk[s] = (len<<16) | (b<<8) | t0.  nk[k] = #runs with len > k, k=0..256.
__global__ void seg_kernel(const int* __restrict__ mask,
                           int* __restrict__ slotPk,
                           int* __restrict__ nkArr) {
  __shared__ ushort rT0[64][130];
  __shared__ ushort rLen[64][130];
  __shared__ int rowRuns[64];
  __shared__ int hist[260];
  __shared__ int offs[260];
  __shared__ int totalRuns;
  const int tid = threadIdx.x;
  for (int i = tid; i < 260; i += 256) hist[i] = 0;
  __syncthreads();
  if (tid < 64) {
    const int b = tid;
    int cnt = 0, cur = 0, t0 = 0;
    for (int t = 0; t < 256; ++t) {
      const int m = mask[b * 256 + t];
      if (m != 0) { if (cur == 0) t0 = t; cur++; }
      else if (cur > 0) {
        rT0[b][cnt] = (ushort)t0; rLen[b][cnt] = (ushort)cur;
        atomicAdd(&hist[cur], 1); cnt++; cur = 0;
      }
    }
    if (cur > 0) {
      rT0[b][cnt] = (ushort)t0; rLen[b][cnt] = (ushort)cur;
      atomicAdd(&hist[cur], 1); cnt++;
    }
    rowRuns[b] = cnt;
  }
  __syncthreads();
  if (tid == 0) {
    int acc = 0;
    for (int L = 256; L >= 1; --L) { offs[L] = acc; acc += hist[L]; }
    totalRuns = acc;
  }
  __syncthreads();
  for (int k = tid; k <= 256; k += 256)
    nkArr[k] = (k == 0) ? totalRuns : offs[k];
  __syncthreads();  // nk written before offs is consumed as scatter cursors
  if (tid < 64) {
    const int b = tid;
    const int nr = rowRuns[b];
    for (int i = 0; i < nr; ++i) {
      const int L = rLen[b][i], t0 = rT0[b][i];
      const int pos = atomicAdd(&offs[L], 1);
      slotPk[pos] = (L << 16) | (b << 8) | t0;
    }
  }
}

// ---- fused persistent bidirectional 2-layer LSTM over sorted segments ------
// 256 WGs x 256 thr, 1 WG/CU. grp = bi & 7 -> (dir d, row-stripe). Group =
// 32 col-slice WGs exchanging h through LLC per DEPTH round (not per time
// step): depth k processes the dense prefix of active slots [0, nk[k]) as
// 16-row tiles; tile t handled by stripe (t & 3). Sequential rounds per
// layer ~= max run length (~15-20) instead of 256, and masked positions
// (half of all (b,t)) cost nothing.
__global__ __launch_bounds__(256, 1) void lstm_seg_kernel(
    const ushort* __restrict__ Xf,             // [T*64][1024] fp16 (layer-0 in)
    ushort* __restrict__ O0f,                  // [T*64][1024] fp16 (layer-0 out)
    const ushort* __restrict__ Wih16,          // [L*2*2048][1024] fp16
    const __hip_bfloat16* __restrict__ WhhHi,  // [L*2*2048][512] bf16 hi
    const __hip_bfloat16* __restrict__ WhhLo,  //                bf16 lo
    const float* __restrict__ b_ih, const float* __restrict__ b_hh,
    const int* __restrict__ slotPk,            // [NSLOT_ALL] (len<<16)|(b<<8)|t0
    const int* __restrict__ nkArr,             // [257] active-count per depth
    uint* __restrict__ Hpk,                    // [2 d][2 par][NSLOT2][512] bf16 hi|lo
    float* __restrict__ Cst,                   // [2 d][NSLOT2][512] fp32 cell state
    uint* __restrict__ tags,                   // [8 grp][32 WG] spaced 32 dwords
    uint* __restrict__ gcnt,
    float* __restrict__ out)
{
  extern __shared__ short lds[];
  short* XF = lds;          // 16 x 1024 fp16 (32 KB), granule-swizzled
  short* HH = lds + 16384;  // 16 x 512 bf16 hi (16 KB)
  short* HL = lds + 24576;  // 16 x 512 bf16 lo (16 KB)

  const int tid = threadIdx.x;
  const int w = tid >> 6, l = tid & 63;
  const int lane15 = l & 15, quad = l >> 4;
  const int gn = lane15 >> 2, jn = lane15 & 3;
  const int bi = blockIdx.x;
  const int grp = bi & 7, nc = bi >> 3;
  const int d = grp >> 2, stripe = grp & 3;
  const int j0 = nc * 16;
  const int jcol = j0 + w * 4 + jn;
  const int row16 = tid >> 4, seg = tid & 15;
  uint* mytag = tags + grp * 1024 + nc * 32;
  const uint* grptags = tags + grp * 1024;

  for (int layer = 0; layer < 2; ++layer) {
    if (layer == 1) {   // one-time inter-layer rendezvous (all 256 WGs)
      __builtin_amdgcn_s_waitcnt(0);
      __syncthreads();
      if (tid == 0) {
        __hip_atomic_fetch_add(gcnt, 1u, __ATOMIC_RELAXED, __HIP_MEMORY_SCOPE_AGENT);
        while (__hip_atomic_load(gcnt, __ATOMIC_RELAXED, __HIP_MEMORY_SCOPE_AGENT) < 256u)
          __builtin_amdgcn_s_sleep(4);
      }
      __syncthreads();
    }

    // ---- register-resident weights: wih (fp16), whh (bf16 hi+lo) ----
    const size_t rw = (size_t)((layer * 2 + d) * 2048 + gn * 512 + jcol);
    half8 wih[32];
    {
      const ushort* pw = Wih16 + rw * 1024 + quad * 8;
      #pragma unroll
      for (int kk = 0; kk < 32; ++kk) wih[kk] = *(const half8*)(pw + kk * 32);
    }
    short8 whh_h[16], whh_l[16];
    {
      const __hip_bfloat16* ph = WhhHi + rw * 512 + quad * 8;
      const __hip_bfloat16* pl = WhhLo + rw * 512 + quad * 8;
      #pragma unroll
      for (int kk = 0; kk < 16; ++kk) {
        whh_h[kk] = *(const short8*)(ph + kk * 32);
        whh_l[kk] = *(const short8*)(pl + kk * 32);
      }
    }
    float bias_c[4];
    #pragma unroll
    for (int g2 = 0; g2 < 4; ++g2) {
      int o = (layer * 2 + d) * 2048 + g2 * 512 + jcol;
      bias_c[g2] = b_ih[o] + b_hh[o];
    }
    const ushort* Xp = layer ? O0f : Xf;
    const uint base = (uint)(layer * 1000);  // layer-0 tags stay < 1000

    for (int k = 0; ; ++k) {
      const int n = nkArr[k];
      const int ntt = (n + 15) >> 4;
      if (stripe >= ntt) break;            // monotone: once empty, done
      const int cur = k & 1, nxt = cur ^ 1;

      // ---- wait for h(depth k-1) from all 32 group WGs ----
      if (k > 0) {
        if (w == 0) {
          const uint need = base + (uint)k;
          for (;;) {
            uint v = 0xffffffffu;
            if (l < 32)
              v = __hip_atomic_load(grptags + l * 32, __ATOMIC_RELAXED, __HIP_MEMORY_SCOPE_AGENT);
            if (__all((int)(v >= need))) break;
            __builtin_amdgcn_s_sleep(1);
          }
        }
        __atomic_signal_fence(__ATOMIC_ACQUIRE);
        __builtin_amdgcn_s_barrier();
      }

      for (int tile = stripe; tile < ntt; tile += 4) {
        const int s0 = tile << 4;

        // ---- A) stage gathered X rows + h rows into LDS ----
        {
          const int srow = s0 + row16;
          const int srh = (srow < n) ? srow : (n - 1);   // clamp: dup last row
          const int pk = slotPk[srh];
          const int lenR = pk >> 16, bR = (pk >> 8) & 255, t0R = pk & 255;
          const int tR = d ? (t0R + lenR - 1 - k) : (t0R + k);
          const ushort* xrow = Xp + (size_t)(tR * 64 + bR) * 1024;
          #pragma unroll
          for (int gi = 0; gi < 8; ++gi) {
            int g = seg + gi * 16;                       // granule 0..127
            uint4 v = *(const uint4*)(xrow + g * 8);
            *(uint4*)(XF + row16 * 1024 + ((g ^ row16) & 127) * 8) = v;
          }
          if (k > 0) {
            const uint* hrow = Hpk + (((size_t)d * 2 + cur) * NSLOT2 + srh) * 512;
            #pragma unroll
            for (int gi = 0; gi < 4; ++gi) {
              int g = seg + gi * 16;                     // granule 0..63
              const u64* p = (const u64*)(hrow + g * 8);
              u64 q0 = __hip_atomic_load(p + 0, __ATOMIC_RELAXED, __HIP_MEMORY_SCOPE_AGENT);
              u64 q1 = __hip_atomic_load(p + 1, __ATOMIC_RELAXED, __HIP_MEMORY_SCOPE_AGENT);
              u64 q2 = __hip_atomic_load(p + 2, __ATOMIC_RELAXED, __HIP_MEMORY_SCOPE_AGENT);
              u64 q3 = __hip_atomic_load(p + 3, __ATOMIC_RELAXED, __HIP_MEMORY_SCOPE_AGENT);
              uint vv[8];
              vv[0] = (uint)q0; vv[1] = (uint)(q0 >> 32); vv[2] = (uint)q1; vv[3] = (uint)(q1 >> 32);
              vv[4] = (uint)q2; vv[5] = (uint)(q2 >> 32); vv[6] = (uint)q3; vv[7] = (uint)(q3 >> 32);
              short8 hh8, hl8;
              #pragma unroll
              for (int e = 0; e < 8; ++e) { hh8[e] = (short)(vv[e] & 0xffffu); hl8[e] = (short)(vv[e] >> 16); }
              int o = row16 * 512 + ((g ^ row16) & 63) * 8;
              *(short8*)(HH + o) = hh8;
              *(short8*)(HL + o) = hl8;
            }
          }
        }
        __syncthreads();

        // ---- B) x-projection MFMA (2 chains) + recurrent MFMA (3 chains) ----
        f32x4 a0 = {}, a1 = {}, a2 = {}, a3 = {}, a4 = {};
        #pragma unroll
        for (int kk = 0; kk < 32; ++kk) {
          int o = lane15 * 1024 + (((kk * 4 + quad) ^ lane15) & 127) * 8;
          half8 xa = *(const half8*)(XF + o);
          if (kk & 1) a1 = MFMA_F16(xa, wih[kk], a1, 0, 0, 0);
          else        a0 = MFMA_F16(xa, wih[kk], a0, 0, 0, 0);
        }
        if (k > 0) {
          #pragma unroll
          for (int kk = 0; kk < 16; ++kk) {
            int o = lane15 * 512 + (((kk * 4 + quad) ^ lane15) & 63) * 8;
            short8 hh = *(const short8*)(HH + o);
            short8 hl = *(const short8*)(HL + o);
            a2 = MFMA_BF16(hh, whh_h[kk], a2, 0, 0, 0);
            a3 = MFMA_BF16(hh, whh_l[kk], a3, 0, 0, 0);
            a4 = MFMA_BF16(hl, whh_h[kk], a4, 0, 0, 0);
          }
        }
        f32x4 gsum = (a0 + a1) + (a2 + a3) + a4;

        // ---- C) gather 4 gates intra-wave, update state, publish ----
        f32x4 p1v, p2v, p3v;
        #pragma unroll
        for (int e = 0; e < 4; ++e) {
          p1v[e] = __shfl_xor(gsum[e], 4);
          p2v[e] = __shfl_xor(gsum[e], 8);
          p3v[e] = __shfl_xor(gsum[e], 12);
        }
        f32x4 Gi = (gn == 0) ? gsum : (gn == 1) ? p1v : (gn == 2) ? p2v : p3v;
        f32x4 Gf = (gn == 0) ? p1v : (gn == 1) ? gsum : (gn == 2) ? p3v : p2v;
        f32x4 Gg = (gn == 0) ? p2v : (gn == 1) ? p3v : (gn == 2) ? gsum : p1v;
        f32x4 Go = (gn == 0) ? p3v : (gn == 1) ? p2v : (gn == 2) ? p1v : gsum;

        #pragma unroll
        for (int r = 0; r < 4; ++r) {
          const int slot = s0 + quad * 4 + r;
          const bool act = slot < n;
          const int pk = slotPk[act ? slot : 0];
          const int lenR = pk >> 16, bR = (pk >> 8) & 255, t0R = pk & 255;
          const int tR = d ? (t0R + lenR - 1 - k) : (t0R + k);

          float cprev = 0.0f;
          if (k > 0 && act)
            cprev = Cst[((size_t)d * NSLOT2 + slot) * 512 + jcol];

          float gi = Gi[r] + bias_c[0];
          float gf = Gf[r] + bias_c[1];
          float gg = Gg[r] + bias_c[2];
          float go = Go[r] + bias_c[3];
          float cn = sigf(gf) * cprev + sigf(gi) * tanh_fast(gg);
          float h  = sigf(go) * tanh_fast(cn);
          // within a run, mask is 1 throughout: no mask multiply needed

          const bool liveNext = act && (lenR > k + 1);

          uint myh = f2h16u(h);
          uint oth = (uint)__shfl_xor((int)myh, 1);
          if (gn == 0) {
            if (liveNext) {
              Cst[((size_t)d * NSLOT2 + slot) * 512 + jcol] = cn;
              ushort uh = f2bfu(h);
              ushort ul = f2bfu(h - bfu2f(uh));
              uint pkh = (uint)uh | ((uint)ul << 16);
              size_t ho = (((size_t)d * 2 + nxt) * NSLOT2 + slot) * 512 + jcol;
              __hip_atomic_store(Hpk + ho, pkh, __ATOMIC_RELAXED, __HIP_MEMORY_SCOPE_AGENT);
            }
            if (act) {
              size_t oo = (size_t)(tR * 64 + bR) * 1024 + d * 512 + jcol;
              if (layer == 0) {
                if (!(jn & 1))
                  __hip_atomic_store((uint*)O0f + (oo >> 1), myh | (oth << 16),
                                     __ATOMIC_RELAXED, __HIP_MEMORY_SCOPE_AGENT);
              } else {
                out[oo] = h;
              }
            }
          }
        }
        __syncthreads();   // protect LDS before next tile's staging
      }

      // ---- round end: drain publishes, bump tag ----
      __atomic_signal_fence(__ATOMIC_SEQ_CST);
      __builtin_amdgcn_s_waitcnt(0);      // publishes ACKed at LLC
      __builtin_amdgcn_s_barrier();       // whole WG drained
      if (w == 0 && l == 0)
        __hip_atomic_store(mytag, base + (uint)k + 1u, __ATOMIC_RELAXED, __HIP_MEMORY_SCOPE_AGENT);
    }
  }
}

// ---- host ------------------------------------------------------------------
extern "C" void kernel_launch(void* const* d_in, const int* in_sizes, int n_in,
                              void* d_out, int out_size, void* d_ws, size_t ws_size,
                              hipStream_t stream) {
  const float* x    = (const float*)d_in[0];
  const int*   mask = (const int*)  d_in[1];
  const float* w_ih = (const float*)d_in[2];
  const float* w_hh = (const float*)d_in[3];
  const float* b_ih = (const float*)d_in[4];
  const float* b_hh = (const float*)d_in[5];
  float* outp = (float*)d_out;

  char* ws = (char*)d_ws;
  size_t off = 0;
  auto take = [&](size_t bytes) -> char* {
    char* p = ws + off;
    off += (bytes + 255) & ~(size_t)255;
    return p;
  };
  const size_t NX   = (size_t)T_SEQ * NB * KIN;      // 16.7M
  const size_t NWIH = (size_t)2 * 2 * 2048 * 1024;
  const size_t NWHH = (size_t)2 * 2 * 2048 * 512;
  const size_t NHPK = (size_t)2 * 2 * NSLOT2 * 512;  // dwords
  const size_t NCST = (size_t)2 * NSLOT2 * 512;      // floats

  ushort*         Xf    = (ushort*)        take(NX * 2);     // 33.5 MB
  ushort*         O0f   = (ushort*)        take(NX * 2);     // 33.5 MB
  ushort*         Wih16 = (ushort*)        take(NWIH * 2);   // 16.8 MB
  __hip_bfloat16* WhhHi = (__hip_bfloat16*)take(NWHH * 2);   //  8.4 MB
  __hip_bfloat16* WhhLo = (__hip_bfloat16*)take(NWHH * 2);   //  8.4 MB
  uint*           Hpk   = (uint*)          take(NHPK * 4);   // 45.1 MB
  float*          Cst   = (float*)         take(NCST * 4);   // 22.5 MB
  int*            slotPk= (int*)           take(NSLOT_ALL * 4);
  int*            nkArr = (int*)           take(260 * 4);
  uint*           tags  = (uint*)          take(8 * 1024 * 4);
  uint*           gcnt  = (uint*)          take(256);

  hipMemsetAsync(tags, 0, 8 * 1024 * 4, stream);
  hipMemsetAsync(gcnt, 0, 256, stream);
  hipMemsetAsync(d_out, 0, (size_t)out_size, stream);  // masked positions output 0

  { int n = (int)NX;   conv_f16_kernel<<<(n + 255) / 256, 256, 0, stream>>>(x,    Xf,    n); }
  { int n = (int)NWIH; conv_f16_kernel<<<(n + 255) / 256, 256, 0, stream>>>(w_ih, Wih16, n); }
  { int n = (int)NWHH; split_kernel<<<(n + 255) / 256, 256, 0, stream>>>(w_hh, WhhHi, WhhLo, n); }
  seg_kernel<<<1, 256, 0, stream>>>(mask, slotPk, nkArr);

  lstm_seg_kernel<<<256, 256, 65536, stream>>>(
      Xf, O0f, Wih16, WhhHi, WhhLo, b_ih, b_hh, slotPk, nkArr,
      Hpk, Cst, tags, gcnt, outp);
}

// Round 3
// 1934.017 us; speedup vs baseline: 2.3542x; 1.2988x over previous
//
#include <hip/hip_runtime.h>
#include <hip/hip_bf16.h>

typedef short short8 __attribute__((ext_vector_type(8)));
typedef _Float16 half8 __attribute__((ext_vector_type(8)));
typedef float f32x4 __attribute__((ext_vector_type(4)));
typedef unsigned int uint;
typedef unsigned short ushort;
typedef unsigned long long u64;

static constexpr int T_SEQ = 256;
static constexpr int NB    = 64;
static constexpr int HDIM  = 512;
static constexpr int KIN   = 1024;
static constexpr int NSLOT_ALL = 8192;  // max #runs (len>=1) over 64x256 grid
static constexpr int NSLOT2    = 5504;  // max #runs with len>=2

#define MFMA_BF16 __builtin_amdgcn_mfma_f32_16x16x32_bf16
#define MFMA_F16  __builtin_amdgcn_mfma_f32_16x16x32_f16

__device__ __forceinline__ float sigf(float x) { return 1.0f / (1.0f + __expf(-x)); }
__device__ __forceinline__ float tanh_fast(float x) {
  x = fminf(fmaxf(x, -15.0f), 15.0f);
  float e = __expf(2.0f * x);
  return (e - 1.0f) / (e + 1.0f);
}
__device__ __forceinline__ ushort f2bfu(float v) {
  __hip_bfloat16 b = __float2bfloat16(v);
  ushort u; __builtin_memcpy(&u, &b, 2); return u;
}
__device__ __forceinline__ float bfu2f(ushort u) {
  __hip_bfloat16 b; __builtin_memcpy(&b, &u, 2); return __bfloat162float(b);
}
__device__ __forceinline__ ushort f2h16u(float v) {
  _Float16 h = (_Float16)v;
  ushort u; __builtin_memcpy(&u, &h, 2); return u;
}
// async global->LDS 16B: lane l writes ldsbase + l*16 (wave-uniform lds ptr)
__device__ __forceinline__ void gll16(const void* g, void* l) {
  __builtin_amdgcn_global_load_lds(
      (const __attribute__((address_space(1))) uint*)g,
      (__attribute__((address_space(3))) uint*)l, 16, 0, 0);
}

// ---- fp32 -> fp16 (ushort bits) -------------------------------------------
__global__ void conv_f16_kernel(const float* __restrict__ src,
                                ushort* __restrict__ dst, int n) {
  int i = blockIdx.x * blockDim.x + threadIdx.x;
  if (i < n) dst[i] = f2h16u(src[i]);
}

// ---- fp32 -> bf16 hi + lo split (for W_hh 3-term path) --------------------
__global__ void split_kernel(const float* __restrict__ src,
                             __hip_bfloat16* __restrict__ hi,
                             __hip_bfloat16* __restrict__ lo, int n) {
  int i = blockIdx.x * blockDim.x + threadIdx.x;
  if (i < n) {
    float v = src[i];
    __hip_bfloat16 h = __float2bfloat16(v);
    hi[i] = h;
    lo[i] = __float2bfloat16(v - __bfloat162float(h));
  }
}

// ---- mask segmentation + counting-sort by length (desc) --------------------
// Zero mask resets (h,c): recurrence factorizes into independent runs of
// consecutive mask=1. Sorted desc, active set at depth k = prefix [0,nk[k]).
// slotPk[s] = (len<<16)|(b<<8)|t0.  nkArr[k] = #runs with len > k.
__global__ void seg_kernel(const int* __restrict__ mask,
                           int* __restrict__ slotPk,
                           int* __restrict__ nkArr) {
  __shared__ ushort rT0[64][130];
  __shared__ ushort rLen[64][130];
  __shared__ int rowRuns[64];
  __shared__ int hist[260];
  __shared__ int offs[260];
  __shared__ int totalRuns;
  const int tid = threadIdx.x;
  for (int i = tid; i < 260; i += 256) hist[i] = 0;
  __syncthreads();
  if (tid < 64) {
    const int b = tid;
    int cnt = 0, cur = 0, t0 = 0;
    for (int t = 0; t < 256; ++t) {
      const int m = mask[b * 256 + t];
      if (m != 0) { if (cur == 0) t0 = t; cur++; }
      else if (cur > 0) {
        rT0[b][cnt] = (ushort)t0; rLen[b][cnt] = (ushort)cur;
        atomicAdd(&hist[cur], 1); cnt++; cur = 0;
      }
    }
    if (cur > 0) {
      rT0[b][cnt] = (ushort)t0; rLen[b][cnt] = (ushort)cur;
      atomicAdd(&hist[cur], 1); cnt++;
    }
    rowRuns[b] = cnt;
  }
  __syncthreads();
  if (tid == 0) {
    int acc = 0;
    for (int L = 256; L >= 1; --L) { offs[L] = acc; acc += hist[L]; }
    totalRuns = acc;
  }
  __syncthreads();
  for (int k = tid; k <= 256; k += 256)
    nkArr[k] = (k == 0) ? totalRuns : offs[k];
  __syncthreads();
  if (tid < 64) {
    const int b = tid;
    const int nr = rowRuns[b];
    for (int i = 0; i < nr; ++i) {
      const int L = rLen[b][i], t0 = rT0[b][i];
      const int pos = atomicAdd(&offs[L], 1);
      slotPk[pos] = (L << 16) | (b << 8) | t0;
    }
  }
}

// ---- fused persistent bidirectional 2-layer LSTM over sorted segments ------
// 64 KiB LDS (launches without hipFuncSetAttribute): single X buf (32K) +
// single H hi/lo buf (32K). Pipelining within the tile:
//   top:   issue h(t+1) agent loads -> hq regs (T14), Cst prefetch (tile t)
//   xproj MFMA (X tile t) ; recurrent MFMA (H tile t)
//   barrier2 (X,H reads complete WG-wide)
//   issue gll16 X(t+1) into X buf ; ds_write hq -> H buf (t+1)
//   gates + publish (covers gll16 latency)
//   barrier1 (__syncthreads: drains gll16 + ds_writes)
__global__ __launch_bounds__(256, 1) void lstm_seg_kernel(
    const ushort* __restrict__ Xf,
    ushort* __restrict__ O0f,
    const ushort* __restrict__ Wih16,
    const __hip_bfloat16* __restrict__ WhhHi,
    const __hip_bfloat16* __restrict__ WhhLo,
    const float* __restrict__ b_ih, const float* __restrict__ b_hh,
    const int* __restrict__ slotPk,
    const int* __restrict__ nkArr,
    uint* __restrict__ Hpk,                    // [2 d][2 par][NSLOT2][512] bf16 hi|lo
    float* __restrict__ Cst,                   // [2 d][NSLOT2][512] fp32
    uint* __restrict__ tags,
    uint* __restrict__ gcnt,
    float* __restrict__ out)
{
  extern __shared__ short lds[];
  short* XF = lds;          // 16 x 1024 fp16 (32 KB), granule-swizzled
  short* HH = lds + 16384;  // 16 x 512 bf16 hi (16 KB)
  short* HL = lds + 24576;  // 16 x 512 bf16 lo (16 KB)

  const int tid = threadIdx.x;
  const int w = tid >> 6, l = tid & 63;
  const int lane15 = l & 15, quad = l >> 4;
  const int gn = lane15 >> 2, jn = lane15 & 3;
  const int bi = blockIdx.x;
  const int grp = bi & 7, nc = bi >> 3;
  const int d = grp >> 2, stripe = grp & 3;
  const int j0 = nc * 16;
  const int jcol = j0 + w * 4 + jn;
  const int row16 = tid >> 4, seg = tid & 15;
  uint* mytag = tags + grp * 1024 + nc * 32;
  const uint* grptags = tags + grp * 1024;

  u64 hq[16];  // h(t+1) prefetch registers (raw packed bf16 hi|lo)

  for (int layer = 0; layer < 2; ++layer) {
    if (layer == 1) {   // one-time inter-layer rendezvous (all 256 WGs)
      __builtin_amdgcn_s_waitcnt(0);
      __syncthreads();
      if (tid == 0) {
        __hip_atomic_fetch_add(gcnt, 1u, __ATOMIC_RELAXED, __HIP_MEMORY_SCOPE_AGENT);
        while (__hip_atomic_load(gcnt, __ATOMIC_RELAXED, __HIP_MEMORY_SCOPE_AGENT) < 256u)
          __builtin_amdgcn_s_sleep(4);
      }
      __syncthreads();
    }

    // ---- register-resident weights: wih (fp16), whh (bf16 hi+lo) ----
    const size_t rw = (size_t)((layer * 2 + d) * 2048 + gn * 512 + jcol);
    half8 wih[32];
    {
      const ushort* pw = Wih16 + rw * 1024 + quad * 8;
      #pragma unroll
      for (int kk = 0; kk < 32; ++kk) wih[kk] = *(const half8*)(pw + kk * 32);
    }
    short8 whh_h[16], whh_l[16];
    {
      const __hip_bfloat16* ph = WhhHi + rw * 512 + quad * 8;
      const __hip_bfloat16* pl = WhhLo + rw * 512 + quad * 8;
      #pragma unroll
      for (int kk = 0; kk < 16; ++kk) {
        whh_h[kk] = *(const short8*)(ph + kk * 32);
        whh_l[kk] = *(const short8*)(pl + kk * 32);
      }
    }
    float bias_c[4];
    #pragma unroll
    for (int g2 = 0; g2 < 4; ++g2) {
      int o = (layer * 2 + d) * 2048 + g2 * 512 + jcol;
      bias_c[g2] = b_ih[o] + b_hh[o];
    }
    const ushort* Xp = layer ? O0f : Xf;
    const uint base = (uint)(layer * 1000);

    // X staging: wave w stages rows 4w..4w+3 (2 half-rows each) via gll16.
    // LDS slot s holds global granule s^row (rt<16 so the &127 XOR splits as
    // (s&64) + ((s&63)^rt)); achieved by inverse-swizzling the per-lane
    // GLOBAL address while the LDS dest stays linear (guide rule #21).
    auto stageX = [&](int s0t, int n, int k) {
      #pragma unroll
      for (int j = 0; j < 8; ++j) {
        const int rt = 4 * w + (j >> 1);
        const int hb = j & 1;
        int srow = s0t + rt; if (srow >= n) srow = n - 1;
        const int pk = slotPk[srow];               // wave-uniform (s_load)
        const int lenR = pk >> 16, bR = (pk >> 8) & 255, t0R = pk & 255;
        const int tR = d ? (t0R + lenR - 1 - k) : (t0R + k);
        const ushort* src = Xp + (size_t)(tR * 64 + bR) * 1024
                               + (size_t)(((l ^ rt) + 64 * hb) * 8);
        gll16(src, XF + rt * 1024 + hb * 512);
      }
    };
    auto loadH = [&](int s0t, int n, int par) {
      int srow = s0t + row16; if (srow >= n) srow = n - 1;
      const uint* hrow = Hpk + (((size_t)d * 2 + par) * NSLOT2 + srow) * 512;
      #pragma unroll
      for (int gi = 0; gi < 4; ++gi) {
        const u64* p = (const u64*)(hrow + (seg + gi * 16) * 8);
        hq[gi*4+0] = __hip_atomic_load(p + 0, __ATOMIC_RELAXED, __HIP_MEMORY_SCOPE_AGENT);
        hq[gi*4+1] = __hip_atomic_load(p + 1, __ATOMIC_RELAXED, __HIP_MEMORY_SCOPE_AGENT);
        hq[gi*4+2] = __hip_atomic_load(p + 2, __ATOMIC_RELAXED, __HIP_MEMORY_SCOPE_AGENT);
        hq[gi*4+3] = __hip_atomic_load(p + 3, __ATOMIC_RELAXED, __HIP_MEMORY_SCOPE_AGENT);
      }
    };
    auto writeH = [&]() {
      #pragma unroll
      for (int gi = 0; gi < 4; ++gi) {
        const int g = seg + gi * 16;
        uint vv[8];
        vv[0] = (uint)hq[gi*4+0]; vv[1] = (uint)(hq[gi*4+0] >> 32);
        vv[2] = (uint)hq[gi*4+1]; vv[3] = (uint)(hq[gi*4+1] >> 32);
        vv[4] = (uint)hq[gi*4+2]; vv[5] = (uint)(hq[gi*4+2] >> 32);
        vv[6] = (uint)hq[gi*4+3]; vv[7] = (uint)(hq[gi*4+3] >> 32);
        short8 hh8, hl8;
        #pragma unroll
        for (int e = 0; e < 8; ++e) { hh8[e] = (short)(vv[e] & 0xffffu); hl8[e] = (short)(vv[e] >> 16); }
        const int o = row16 * 512 + ((g ^ row16) & 63) * 8;
        *(short8*)(HH + o) = hh8;
        *(short8*)(HL + o) = hl8;
      }
    };

    for (int k = 0; ; ++k) {
      const int n = nkArr[k];
      const int ntt = (n + 15) >> 4;
      if (stripe >= ntt) break;            // group peers share stripe: same exit
      const int hpar = k & 1, hnxt = hpar ^ 1;
      const int m = (ntt - stripe + 3) >> 2;

      // ---- wait for h(depth k-1) from all 32 group WGs ----
      if (k > 0) {
        if (w == 0) {
          const uint need = base + (uint)k;
          for (;;) {
            uint v = 0xffffffffu;
            if (l < 32)
              v = __hip_atomic_load(grptags + l * 32, __ATOMIC_RELAXED, __HIP_MEMORY_SCOPE_AGENT);
            if (__all((int)(v >= need))) break;
            __builtin_amdgcn_s_sleep(1);
          }
        }
        __atomic_signal_fence(__ATOMIC_ACQUIRE);
        __builtin_amdgcn_s_barrier();
      }

      // ---- round prologue: stage first tile ----
      stageX(stripe << 4, n, k);
      if (k > 0) { loadH(stripe << 4, n, hpar); writeH(); }
      __syncthreads();

      for (int i = 0; i < m; ++i) {
        const int t = stripe + 4 * i;
        const int s0 = t << 4;
        const bool pf = (i + 1 < m);       // WG-uniform
        const int s0n = (t + 4) << 4;

        // ---- tile top: issue h(t+1) -> regs, Cst(t) prefetch ----
        if (k > 0 && pf) loadH(s0n, n, hpar);
        float cpre[4];
        #pragma unroll
        for (int r = 0; r < 4; ++r) {
          const int slot = s0 + quad * 4 + r;
          cpre[r] = (k > 0 && slot < n)
                        ? Cst[((size_t)d * NSLOT2 + slot) * 512 + jcol] : 0.0f;
        }

        // ---- x-projection MFMA from XF (4 chains) ----
        f32x4 a0 = {}, a1 = {}, a2 = {}, a3 = {}, a4 = {}, a5 = {}, a6 = {};
        #pragma unroll
        for (int kk = 0; kk < 32; ++kk) {
          int o = lane15 * 1024 + (((kk * 4 + quad) ^ lane15) & 127) * 8;
          half8 xa = *(const half8*)(XF + o);
          if      ((kk & 3) == 0) a0 = MFMA_F16(xa, wih[kk], a0, 0, 0, 0);
          else if ((kk & 3) == 1) a1 = MFMA_F16(xa, wih[kk], a1, 0, 0, 0);
          else if ((kk & 3) == 2) a5 = MFMA_F16(xa, wih[kk], a5, 0, 0, 0);
          else                    a6 = MFMA_F16(xa, wih[kk], a6, 0, 0, 0);
        }
        // ---- recurrent MFMA from HH/HL (3 chains, bf16 3-term) ----
        if (k > 0) {
          #pragma unroll
          for (int kk = 0; kk < 16; ++kk) {
            int o = lane15 * 512 + (((kk * 4 + quad) ^ lane15) & 63) * 8;
            short8 hh = *(const short8*)(HH + o);
            short8 hl = *(const short8*)(HL + o);
            a2 = MFMA_BF16(hh, whh_h[kk], a2, 0, 0, 0);
            a3 = MFMA_BF16(hh, whh_l[kk], a3, 0, 0, 0);
            a4 = MFMA_BF16(hl, whh_h[kk], a4, 0, 0, 0);
          }
        }
        f32x4 gsum = ((a0 + a1) + (a5 + a6)) + ((a2 + a3) + a4);

        __syncthreads();   // barrier2: all waves done reading XF/HH/HL

        // ---- stage tile t+1 while gates run ----
        if (pf) stageX(s0n, n, k);
        if (k > 0 && pf) writeH();

        // ---- gather 4 gates intra-wave, update state, publish ----
        f32x4 p1v, p2v, p3v;
        #pragma unroll
        for (int e = 0; e < 4; ++e) {
          p1v[e] = __shfl_xor(gsum[e], 4);
          p2v[e] = __shfl_xor(gsum[e], 8);
          p3v[e] = __shfl_xor(gsum[e], 12);
        }
        f32x4 Gi = (gn == 0) ? gsum : (gn == 1) ? p1v : (gn == 2) ? p2v : p3v;
        f32x4 Gf = (gn == 0) ? p1v : (gn == 1) ? gsum : (gn == 2) ? p3v : p2v;
        f32x4 Gg = (gn == 0) ? p2v : (gn == 1) ? p3v : (gn == 2) ? gsum : p1v;
        f32x4 Go = (gn == 0) ? p3v : (gn == 1) ? p2v : (gn == 2) ? p1v : gsum;

        #pragma unroll
        for (int r = 0; r < 4; ++r) {
          const int slot = s0 + quad * 4 + r;
          const bool act = slot < n;
          const int pk = slotPk[act ? slot : 0];
          const int lenR = pk >> 16, bR = (pk >> 8) & 255, t0R = pk & 255;
          const int tR = d ? (t0R + lenR - 1 - k) : (t0R + k);

          float gi = Gi[r] + bias_c[0];
          float gf = Gf[r] + bias_c[1];
          float gg = Gg[r] + bias_c[2];
          float go = Go[r] + bias_c[3];
          float cn = sigf(gf) * cpre[r] + sigf(gi) * tanh_fast(gg);
          float h  = sigf(go) * tanh_fast(cn);
          // within a run, mask is 1 throughout: no mask multiply needed

          const bool liveNext = act && (lenR > k + 1);

          uint myh = f2h16u(h);
          uint oth = (uint)__shfl_xor((int)myh, 1);
          if (gn == 0) {
            if (liveNext) {
              Cst[((size_t)d * NSLOT2 + slot) * 512 + jcol] = cn;
              ushort uh = f2bfu(h);
              ushort ul = f2bfu(h - bfu2f(uh));
              uint pkh = (uint)uh | ((uint)ul << 16);
              size_t ho = (((size_t)d * 2 + hnxt) * NSLOT2 + slot) * 512 + jcol;
              __hip_atomic_store(Hpk + ho, pkh, __ATOMIC_RELAXED, __HIP_MEMORY_SCOPE_AGENT);
            }
            if (act) {
              size_t oo = (size_t)(tR * 64 + bR) * 1024 + d * 512 + jcol;
              if (layer == 0) {
                if (!(jn & 1))
                  __hip_atomic_store((uint*)O0f + (oo >> 1), myh | (oth << 16),
                                     __ATOMIC_RELAXED, __HIP_MEMORY_SCOPE_AGENT);
              } else {
                out[oo] = h;
              }
            }
          }
        }
        __syncthreads();   // barrier1: drains gll16 X(t+1) + H ds_writes
      }

      // ---- round end: drain publishes, bump tag ----
      __atomic_signal_fence(__ATOMIC_SEQ_CST);
      __builtin_amdgcn_s_waitcnt(0);      // publishes ACKed at LLC
      __builtin_amdgcn_s_barrier();
      if (w == 0 && l == 0)
        __hip_atomic_store(mytag, base + (uint)k + 1u, __ATOMIC_RELAXED, __HIP_MEMORY_SCOPE_AGENT);
    }
  }
}

// ---- host ------------------------------------------------------------------
extern "C" void kernel_launch(void* const* d_in, const int* in_sizes, int n_in,
                              void* d_out, int out_size, void* d_ws, size_t ws_size,
                              hipStream_t stream) {
  const float* x    = (const float*)d_in[0];
  const int*   mask = (const int*)  d_in[1];
  const float* w_ih = (const float*)d_in[2];
  const float* w_hh = (const float*)d_in[3];
  const float* b_ih = (const float*)d_in[4];
  const float* b_hh = (const float*)d_in[5];
  float* outp = (float*)d_out;

  char* ws = (char*)d_ws;
  size_t off = 0;
  auto take = [&](size_t bytes) -> char* {
    char* p = ws + off;
    off += (bytes + 255) & ~(size_t)255;
    return p;
  };
  const size_t NX   = (size_t)T_SEQ * NB * KIN;
  const size_t NWIH = (size_t)2 * 2 * 2048 * 1024;
  const size_t NWHH = (size_t)2 * 2 * 2048 * 512;
  const size_t NHPK = (size_t)2 * 2 * NSLOT2 * 512;
  const size_t NCST = (size_t)2 * NSLOT2 * 512;

  ushort*         Xf    = (ushort*)        take(NX * 2);
  ushort*         O0f   = (ushort*)        take(NX * 2);
  ushort*         Wih16 = (ushort*)        take(NWIH * 2);
  __hip_bfloat16* WhhHi = (__hip_bfloat16*)take(NWHH * 2);
  __hip_bfloat16* WhhLo = (__hip_bfloat16*)take(NWHH * 2);
  uint*           Hpk   = (uint*)          take(NHPK * 4);
  float*          Cst   = (float*)         take(NCST * 4);
  int*            slotPk= (int*)           take(NSLOT_ALL * 4);
  int*            nkArr = (int*)           take(260 * 4);
  uint*           tags  = (uint*)          take(8 * 1024 * 4);
  uint*           gcnt  = (uint*)          take(256);

  hipMemsetAsync(tags, 0, 8 * 1024 * 4, stream);
  hipMemsetAsync(gcnt, 0, 256, stream);
  hipMemsetAsync(d_out, 0, (size_t)out_size, stream);  // masked positions -> 0

  { int n = (int)NX;   conv_f16_kernel<<<(n + 255) / 256, 256, 0, stream>>>(x,    Xf,    n); }
  { int n = (int)NWIH; conv_f16_kernel<<<(n + 255) / 256, 256, 0, stream>>>(w_ih, Wih16, n); }
  { int n = (int)NWHH; split_kernel<<<(n + 255) / 256, 256, 0, stream>>>(w_hh, WhhHi, WhhLo, n); }
  seg_kernel<<<1, 256, 0, stream>>>(mask, slotPk, nkArr);

  lstm_seg_kernel<<<256, 256, 65536, stream>>>(
      Xf, O0f, Wih16, WhhHi, WhhLo, b_ih, b_hh, slotPk, nkArr,
      Hpk, Cst, tags, gcnt, outp);
}